// Round 1
// baseline (247.095 us; speedup 1.0000x reference)
//
#include <hip/hip_runtime.h>

#define NB     1024
#define NWORLD 2048
#define DDIM   64

typedef __attribute__((ext_vector_type(4))) float f32x4;
typedef __attribute__((ext_vector_type(8))) short bf16x8;

__device__ __forceinline__ short f2bf(float f) {
    union { float f; unsigned u; } v; v.f = f;
    unsigned u = v.u;
    u += 0x7fffu + ((u >> 16) & 1u);   // RNE round to bf16
    return (short)(u >> 16);
}

__device__ __forceinline__ bf16x8 load8_bf(const float* p) {
    const f32x4 a = *reinterpret_cast<const f32x4*>(p);
    const f32x4 b = *reinterpret_cast<const f32x4*>(p + 4);
    bf16x8 r;
    r[0] = f2bf(a[0]); r[1] = f2bf(a[1]); r[2] = f2bf(a[2]); r[3] = f2bf(a[3]);
    r[4] = f2bf(b[0]); r[5] = f2bf(b[1]); r[6] = f2bf(b[2]); r[7] = f2bf(b[3]);
    return r;
}

// One block = one output row r (0..1023) x one 128-world tile.
// 4 waves; each wave owns 32 worlds (2 subtiles of 16) and all 64 d's
// (4 MFMA m-tiles), so the L2-norm over d reduces inside one wave.
__global__ __launch_bounds__(256)
void nullary_fused(const float* __restrict__ worlds,   // [2048][64]
                   const float* __restrict__ W,        // [512][64][64]
                   const int*   __restrict__ nullary,  // [1024][2]
                   float*       __restrict__ out)      // [1024][64][2048]
{
    const int r    = blockIdx.x;
    const int wblk = blockIdx.y;
    const int tid  = threadIdx.x;
    const int wave = tid >> 6;
    const int lane = tid & 63;
    const int col  = lane & 15;   // MFMA N / C-col index
    const int krow = lane >> 4;   // 0..3: K-group for A/B frags, row-group for C

    __shared__ int s_cnt;
    __shared__ int s_list[NB];

    if (tid == 0) s_cnt = 0;
    __syncthreads();
    // parallel scan of nullary[:,0] for matches with this row
    for (int i = tid; i < NB; i += 256) {
        if (nullary[2 * i] == r) {
            int p = atomicAdd(&s_cnt, 1);
            s_list[p] = i;
        }
    }
    __syncthreads();
    const int cnt = s_cnt;
    // sort tiny list (avg ~2) for bit-deterministic accumulation order
    if (tid == 0 && cnt > 1) {
        for (int i = 1; i < cnt; ++i) {
            int v = s_list[i]; int j = i - 1;
            while (j >= 0 && s_list[j] > v) { s_list[j + 1] = s_list[j]; --j; }
            s_list[j + 1] = v;
        }
    }
    __syncthreads();

    const int w0 = wblk * 128 + wave * 32;

    // B fragments (worlds), match-independent: lane needs
    // worlds[w0+sub*16+col][kt*32 + krow*8 + 0..7] -> 8 contiguous f32
    bf16x8 bfrag[2][2];
    #pragma unroll
    for (int sub = 0; sub < 2; ++sub) {
        const float* wp = worlds + (size_t)(w0 + sub * 16 + col) * DDIM + krow * 8;
        bfrag[sub][0] = load8_bf(wp);
        bfrag[sub][1] = load8_bf(wp + 32);
    }

    f32x4 acc[2][4];
    #pragma unroll
    for (int s = 0; s < 2; ++s)
        #pragma unroll
        for (int m = 0; m < 4; ++m)
            acc[s][m] = (f32x4){0.f, 0.f, 0.f, 0.f};

    for (int mi = 0; mi < cnt; ++mi) {
        const int n = s_list[mi];
        const int b = nullary[2 * n + 1];
        const float* Wb = W + (size_t)b * DDIM * DDIM;

        // A fragments: Wb[mt*16+col][kt*32 + krow*8 + 0..7]
        bf16x8 afrag[4][2];
        #pragma unroll
        for (int mt = 0; mt < 4; ++mt) {
            const float* ap = Wb + (size_t)(mt * 16 + col) * DDIM + krow * 8;
            afrag[mt][0] = load8_bf(ap);
            afrag[mt][1] = load8_bf(ap + 32);
        }

        #pragma unroll
        for (int sub = 0; sub < 2; ++sub) {
            f32x4 x[4];
            #pragma unroll
            for (int mt = 0; mt < 4; ++mt) {
                f32x4 c = {0.f, 0.f, 0.f, 0.f};
                c = __builtin_amdgcn_mfma_f32_16x16x32_bf16(afrag[mt][0], bfrag[sub][0], c, 0, 0, 0);
                c = __builtin_amdgcn_mfma_f32_16x16x32_bf16(afrag[mt][1], bfrag[sub][1], c, 0, 0, 0);
                x[mt] = c;
            }
            // sq = sum over all 64 d of x^2 for this lane's world column.
            // lane holds d = mt*16 + krow*4 + j; lanes sharing col differ in krow.
            float p = 0.f;
            #pragma unroll
            for (int mt = 0; mt < 4; ++mt)
                #pragma unroll
                for (int j = 0; j < 4; ++j)
                    p += x[mt][j] * x[mt][j];
            p += __shfl_xor(p, 16, 64);
            p += __shfl_xor(p, 32, 64);
            const float scale = rsqrtf(fmaxf(p, 1e-12f));
            #pragma unroll
            for (int mt = 0; mt < 4; ++mt)
                #pragma unroll
                for (int j = 0; j < 4; ++j)
                    acc[sub][mt][j] += x[mt][j] * scale;
        }
    }

    // write: out[r][d][w], d = mt*16 + krow*4 + j, w = w0 + sub*16 + col
    float* orow = out + (size_t)r * DDIM * NWORLD;
    #pragma unroll
    for (int sub = 0; sub < 2; ++sub) {
        const int w = w0 + sub * 16 + col;
        #pragma unroll
        for (int mt = 0; mt < 4; ++mt) {
            #pragma unroll
            for (int j = 0; j < 4; ++j) {
                const int d = mt * 16 + krow * 4 + j;
                orow[(size_t)d * NWORLD + w] = acc[sub][mt][j];
            }
        }
    }
}

extern "C" void kernel_launch(void* const* d_in, const int* in_sizes, int n_in,
                              void* d_out, int out_size, void* d_ws, size_t ws_size,
                              hipStream_t stream) {
    const float* worlds  = (const float*)d_in[0];
    const float* W       = (const float*)d_in[1];
    const int*   nullary = (const int*)d_in[2];
    float*       out     = (float*)d_out;

    dim3 grid(NB, NWORLD / 128);  // 1024 rows x 16 world-tiles
    nullary_fused<<<grid, 256, 0, stream>>>(worlds, W, nullary, out);
}

// Round 2
// 144.342 us; speedup vs baseline: 1.7119x; 1.7119x over previous
//
#include <hip/hip_runtime.h>

#define NB      1024
#define NWORLD  2048
#define DDIM    64
#define NWMAT   512
#define LISTCAP 32

typedef __attribute__((ext_vector_type(4))) float f32x4;
typedef __attribute__((ext_vector_type(8))) short bf16x8;

__device__ __forceinline__ unsigned short f2bf(float f) {
    union { float f; unsigned u; } v; v.f = f;
    unsigned u = v.u;
    u += 0x7fffu + ((u >> 16) & 1u);   // RNE round to bf16
    return (unsigned short)(u >> 16);
}

// ---- kernel 1: convert W and worlds to bf16 into workspace ----
__global__ __launch_bounds__(256)
void convert_bf16(const float* __restrict__ W, const float* __restrict__ worlds,
                  unsigned short* __restrict__ Wbf, unsigned short* __restrict__ worldsbf)
{
    const int NWE = NWMAT * DDIM * DDIM;   // 2097152 (mult of 8)
    const int NWO = NWORLD * DDIM;         // 131072  (mult of 8)
    int i = (blockIdx.x * 256 + threadIdx.x) * 8;
    if (i >= NWE + NWO) return;
    const float* src; unsigned short* dst; int off;
    if (i < NWE) { src = W;      dst = Wbf;      off = i; }
    else         { src = worlds; dst = worldsbf; off = i - NWE; }
    f32x4 a = *reinterpret_cast<const f32x4*>(src + off);
    f32x4 b = *reinterpret_cast<const f32x4*>(src + off + 4);
    bf16x8 r;
    r[0] = (short)f2bf(a[0]); r[1] = (short)f2bf(a[1]);
    r[2] = (short)f2bf(a[2]); r[3] = (short)f2bf(a[3]);
    r[4] = (short)f2bf(b[0]); r[5] = (short)f2bf(b[1]);
    r[6] = (short)f2bf(b[2]); r[7] = (short)f2bf(b[3]);
    *reinterpret_cast<bf16x8*>(dst + off) = r;
}

// ---- kernel 2: per-row match lists (stores W-index b directly), index-ordered ----
__global__ __launch_bounds__(64)
void build_lists(const int* __restrict__ nullary, int* __restrict__ cntw,
                 int* __restrict__ blist)
{
    const int r = blockIdx.x;
    const int lane = threadIdx.x;
    int base = 0;
    for (int c = 0; c < NB / 64; ++c) {
        const int n = c * 64 + lane;
        const bool m = (nullary[2 * n] == r);
        const unsigned long long mask = __ballot(m);
        if (m) {
            const int pos = base + __popcll(mask & ((1ull << lane) - 1ull));
            if (pos < LISTCAP) blist[r * LISTCAP + pos] = nullary[2 * n + 1];
        }
        base += __popcll(mask);
    }
    if (lane == 0) cntw[r] = (base > LISTCAP ? LISTCAP : base);
}

// ---- kernel 3: main fused gather-GEMM + L2norm + streaming write ----
// block = (wtile, r); 4 waves, each owns 32 worlds x all 64 d.
__global__ __launch_bounds__(256)
void nullary_main(const unsigned short* __restrict__ Wbf,
                  const unsigned short* __restrict__ worldsbf,
                  const int* __restrict__ cntw,
                  const int* __restrict__ blist,
                  float* __restrict__ out)
{
    const int wt  = blockIdx.x;      // 0..15
    const int r   = blockIdx.y;      // 0..1023
    const int tid = threadIdx.x;

    float* obase = out + (size_t)r * DDIM * NWORLD + wt * 128;
    const int drow = tid >> 5;        // 0..7
    const int wl   = (tid & 31) * 4;  // 0..124

    const int cnt = cntw[r];
    if (cnt == 0) {                   // 57% of blocks: pure zero stream
        const f32x4 z = {0.f, 0.f, 0.f, 0.f};
        #pragma unroll
        for (int rd = 0; rd < 8; ++rd) {
            const int d = rd * 8 + drow;
            *reinterpret_cast<f32x4*>(obase + (size_t)d * NWORLD + wl) = z;
        }
        return;
    }

    const int wave = tid >> 6, lane = tid & 63;
    const int col = lane & 15, krow = lane >> 4;
    const int w0 = wt * 128 + wave * 32;

    // B fragments from bf16 worlds: one dwordx4 each
    bf16x8 bfrag[2][2];
    #pragma unroll
    for (int sub = 0; sub < 2; ++sub) {
        const unsigned short* wp = worldsbf + (size_t)(w0 + sub * 16 + col) * DDIM + krow * 8;
        bfrag[sub][0] = *reinterpret_cast<const bf16x8*>(wp);
        bfrag[sub][1] = *reinterpret_cast<const bf16x8*>(wp + 32);
    }

    f32x4 acc[2][4];
    #pragma unroll
    for (int s = 0; s < 2; ++s)
        #pragma unroll
        for (int m = 0; m < 4; ++m)
            acc[s][m] = (f32x4){0.f, 0.f, 0.f, 0.f};

    for (int mi = 0; mi < cnt; ++mi) {
        const int b = blist[r * LISTCAP + mi];
        const unsigned short* Wb = Wbf + (size_t)b * DDIM * DDIM;

        bf16x8 afrag[4][2];
        #pragma unroll
        for (int mt = 0; mt < 4; ++mt) {
            const unsigned short* ap = Wb + (size_t)(mt * 16 + col) * DDIM + krow * 8;
            afrag[mt][0] = *reinterpret_cast<const bf16x8*>(ap);
            afrag[mt][1] = *reinterpret_cast<const bf16x8*>(ap + 32);
        }

        #pragma unroll
        for (int sub = 0; sub < 2; ++sub) {
            f32x4 x[4];
            #pragma unroll
            for (int mt = 0; mt < 4; ++mt) {
                f32x4 c = {0.f, 0.f, 0.f, 0.f};
                c = __builtin_amdgcn_mfma_f32_16x16x32_bf16(afrag[mt][0], bfrag[sub][0], c, 0, 0, 0);
                c = __builtin_amdgcn_mfma_f32_16x16x32_bf16(afrag[mt][1], bfrag[sub][1], c, 0, 0, 0);
                x[mt] = c;
            }
            float p = 0.f;
            #pragma unroll
            for (int mt = 0; mt < 4; ++mt)
                #pragma unroll
                for (int j = 0; j < 4; ++j)
                    p += x[mt][j] * x[mt][j];
            p += __shfl_xor(p, 16, 64);
            p += __shfl_xor(p, 32, 64);
            const float s = rsqrtf(fmaxf(p, 1e-12f));
            #pragma unroll
            for (int mt = 0; mt < 4; ++mt)
                #pragma unroll
                for (int j = 0; j < 4; ++j)
                    acc[sub][mt][j] += x[mt][j] * s;
        }
    }

    // LDS transpose so stores are f32x4 with 512B-contiguous segments.
    // pad=132 floats (row stride 528B, 16B-aligned): writes 2-way (free), reads ok.
    __shared__ float T[DDIM][132];
    #pragma unroll
    for (int sub = 0; sub < 2; ++sub)
        #pragma unroll
        for (int mt = 0; mt < 4; ++mt)
            #pragma unroll
            for (int j = 0; j < 4; ++j)
                T[mt * 16 + krow * 4 + j][wave * 32 + sub * 16 + col] = acc[sub][mt][j];
    __syncthreads();

    #pragma unroll
    for (int rd = 0; rd < 8; ++rd) {
        const int d = rd * 8 + drow;
        const f32x4 v = *reinterpret_cast<const f32x4*>(&T[d][wl]);
        *reinterpret_cast<f32x4*>(obase + (size_t)d * NWORLD + wl) = v;
    }
}

extern "C" void kernel_launch(void* const* d_in, const int* in_sizes, int n_in,
                              void* d_out, int out_size, void* d_ws, size_t ws_size,
                              hipStream_t stream) {
    const float* worlds  = (const float*)d_in[0];
    const float* W       = (const float*)d_in[1];
    const int*   nullary = (const int*)d_in[2];
    float*       out     = (float*)d_out;

    unsigned short* Wbf      = (unsigned short*)d_ws;
    unsigned short* worldsbf = Wbf + (size_t)NWMAT * DDIM * DDIM;   // +4 MB
    int*            cntw     = (int*)(worldsbf + (size_t)NWORLD * DDIM); // +256 KB
    int*            blist    = cntw + NB;

    convert_bf16<<<(NWMAT * DDIM * DDIM + NWORLD * DDIM) / (256 * 8), 256, 0, stream>>>(
        W, worlds, Wbf, worldsbf);
    build_lists<<<NB, 64, 0, stream>>>(nullary, cntw, blist);
    nullary_main<<<dim3(16, NB), 256, 0, stream>>>(Wbf, worldsbf, cntw, blist, out);
}